// Round 8
// baseline (701.671 us; speedup 1.0000x reference)
//
#include <hip/hip_runtime.h>
#include <hip/hip_bf16.h>

typedef __attribute__((ext_vector_type(8))) short s8v;
typedef __attribute__((ext_vector_type(4))) float f4v;
typedef __attribute__((ext_vector_type(16))) float f16v;
typedef __attribute__((ext_vector_type(4))) unsigned int u4v;

#define BATCH 32
#define SEQ   2048
#define DIM   256
#define ORIGIN_OFF ((size_t)BATCH * SEQ * DIM)

// ---- workspace layout (units: bf16 shorts) ----
// xT  [32][256][2048] : x transposed per batch, bf16; q-positions PERMUTED
//                       within each 16-group: pos holds q = swap(bits2,3)(pos)
// wlT [2048 q][256 k] : wl_w^T bf16 (natural order)
// hisT/mlpT [256 n][256 k] bf16
#define XT_OFF  0ull
#define WL_OFF  16777216ull
#define HIS_OFF 17301504ull
#define MLP_OFF 17367040ull

// ---- LDS layout (bytes), total 65536 (2 blocks/CU, 4 waves each) ----
// flash : K dbuf @0      (2 x 16384)  [32 q][512B], chunk-XOR(q&7)
//         X dbuf @32768  (2 x 16384)  [256 d][64B], chunk-XOR((d>>1)&3)
// prolog/epilog alias:
//   QS (Q/agg) [128 p][512B] swizzled chunk-XOR(p&7) @0 (65536)
//   WST gemm W-stage [64 n][512B] @32768 (32768)
//   epilog small: CG @0 (1024), CB @1024, WP @1040, WC @2064
#define BX0   32768
#define WST   32768
#define EP_CB 1024
#define EP_WP 1040
#define EP_WC 2064

__device__ __forceinline__ unsigned short f2bf(float f) {
  __hip_bfloat16 h = __float2bfloat16(f);   // round-to-nearest-even
  return *reinterpret_cast<unsigned short*>(&h);
}
__device__ __forceinline__ f16v mfma32(s8v a, s8v b, f16v c) {
  return __builtin_amdgcn_mfma_f32_32x32x16_bf16(a, b, c, 0, 0, 0);
}
__device__ __forceinline__ unsigned int pk2(float lo, float hi) {
  return (unsigned int)f2bf(lo) | ((unsigned int)f2bf(hi) << 16);
}
// async global->LDS, 16B/lane; LDS dest = wave-uniform base + lane*16
__device__ __forceinline__ void dma16(const void* g, void* l) {
  __builtin_amdgcn_global_load_lds(
      (const __attribute__((address_space(1))) unsigned int*)g,
      (__attribute__((address_space(3))) unsigned int*)l, 16, 0, 0);
}

// ---------------- unified prep kernel ----------------
// 64x64 tile transpose f32 -> bf16 via LDS, chunk-XOR-swizzled.
// xT path applies the bits2<->3 swap permutation within each 16-q group.
// grid.x = 4096 (xT) + 128 (wl) + 16 (his) + 16 (mlp) = 4256
__global__ __launch_bounds__(256) void prep_all(
    const float* __restrict__ x, const float* __restrict__ wl_w,
    const float* __restrict__ his_w, const float* __restrict__ mlp_w,
    unsigned short* __restrict__ ws)
{
  __shared__ unsigned short tile[64][72];   // 144B stride
  const int t = threadIdx.x;
  const int tb = blockIdx.x;
  const float* src; unsigned short* dst; int lds_, ldd_, r0, c0;
  bool isx = false;
  if (tb < 4096) {
    const int b = tb >> 7, rem = tb & 127;
    r0 = (rem >> 2) * 64;  c0 = (rem & 3) * 64;
    src = x + (size_t)b * SEQ * DIM;  lds_ = DIM;
    dst = ws + XT_OFF + (size_t)b * DIM * SEQ;  ldd_ = SEQ;
    isx = true;
  } else if (tb < 4224) {
    const int t2 = tb - 4096;
    r0 = (t2 >> 5) * 64;  c0 = (t2 & 31) * 64;
    src = wl_w;  lds_ = 2048;  dst = ws + WL_OFF;  ldd_ = 256;
  } else if (tb < 4240) {
    const int t2 = tb - 4224;
    r0 = (t2 >> 2) * 64;  c0 = (t2 & 3) * 64;
    src = his_w;  lds_ = 256;  dst = ws + HIS_OFF;  ldd_ = 256;
  } else {
    const int t2 = tb - 4240;
    r0 = (t2 >> 2) * 64;  c0 = (t2 & 3) * 64;
    src = mlp_w;  lds_ = 256;  dst = ws + MLP_OFF;  ldd_ = 256;
  }
  { // phase 1: coalesced row reads, 16B chunks at slot ch^(rr>>4)
    const int rr = t >> 2, cc = (t & 3) * 16;
    const float* s0 = src + (size_t)(r0 + rr) * lds_ + c0 + cc;
    f4v v0 = *(const f4v*)(s0);
    f4v v1 = *(const f4v*)(s0 + 4);
    f4v v2 = *(const f4v*)(s0 + 8);
    f4v v3 = *(const f4v*)(s0 + 12);
    u4v o0, o1;
    o0[0] = pk2(v0[0], v0[1]); o0[1] = pk2(v0[2], v0[3]);
    o0[2] = pk2(v1[0], v1[1]); o0[3] = pk2(v1[2], v1[3]);
    o1[0] = pk2(v2[0], v2[1]); o1[1] = pk2(v2[2], v2[3]);
    o1[2] = pk2(v3[0], v3[1]); o1[3] = pk2(v3[2], v3[3]);
    const int swz = rr >> 4;
    const int ch = cc >> 3;          // 0,2,4,6
    unsigned short* trow = &tile[rr][0];
    *(u4v*)(trow + ((ch ^ swz) << 3)) = o0;
    *(u4v*)(trow + (((ch + 1) ^ swz) << 3)) = o1;
  }
  __syncthreads();
  {
    const int cl = t >> 2, sg = t & 3;
    const int el = cl & 7;
    const int chb = ((cl >> 3) ^ sg) << 3;   // rA>>4 == sg in all cases below
    u4v o0, o1;
    if (isx) { // permuted: output pos e holds source q = sg*16 + swap23(e)
      // pairs (e,e+1) for e even; swap23 keeps bit0: row pairs stay adjacent.
      const int pe0[4] = {0, 2, 8, 10};   // swap23 of e = 0,2,4,6
      const int pe1[4] = {4, 6, 12, 14};  // swap23 of e = 8,10,12,14
      #pragma unroll
      for (int j = 0; j < 4; ++j) {
        const int rA = sg * 16 + pe0[j];
        o0[j] = (unsigned int)tile[rA][chb + el]
              | ((unsigned int)tile[rA + 1][chb + el] << 16);
      }
      #pragma unroll
      for (int j = 0; j < 4; ++j) {
        const int rA = sg * 16 + pe1[j];
        o1[j] = (unsigned int)tile[rA][chb + el]
              | ((unsigned int)tile[rA + 1][chb + el] << 16);
      }
    } else {   // identity order
      #pragma unroll
      for (int j = 0; j < 4; ++j) {
        const int rA = sg * 16 + 2 * j;
        o0[j] = (unsigned int)tile[rA][chb + el]
              | ((unsigned int)tile[rA + 1][chb + el] << 16);
      }
      #pragma unroll
      for (int j = 0; j < 4; ++j) {
        const int rA = sg * 16 + 8 + 2 * j;
        o1[j] = (unsigned int)tile[rA][chb + el]
              | ((unsigned int)tile[rA + 1][chb + el] << 16);
      }
    }
    unsigned short* d0 = dst + (size_t)(c0 + cl) * ldd_ + r0 + sg * 16;
    *(u4v*)d0 = o0;
    *(u4v*)(d0 + 8) = o1;
  }
}

// ---------------- main kernel ----------------

// acc[st*2+nt] += A(regs af, wave's 32 p) @ Wt[n 256][k 256]; 4 DMA-staged
// stages of [64 n][512B] into WST. 32x32x16 MFMAs. n = (st*2+nt)*32 + (l&31).
__device__ __forceinline__ void gemm_stage32(
    const unsigned short* __restrict__ Wt, const s8v (&af)[16],
    f16v (&acc)[8], char* smem_, int wq, int lane)
{
  char* sW = smem_ + WST;
  const int hi = lane >> 5, l31 = lane & 31, l7 = lane & 7;
  for (int st = 0; st < 4; ++st) {
    if (st) __syncthreads();             // prior-stage reads drained
    #pragma unroll
    for (int j = 0; j < 8; ++j) {
      const int row = wq * 16 + 2 * j + hi;
      dma16(Wt + (size_t)(st * 64 + row) * 256 + ((l31 ^ (row & 7)) << 3),
            sW + wq * 8192 + j * 1024);
    }
    __syncthreads();                     // DMA complete (implicit vmcnt(0))
    #pragma unroll
    for (int ks = 0; ks < 16; ++ks) {
      #pragma unroll
      for (int nt = 0; nt < 2; ++nt) {
        s8v bfr = *(const s8v*)(sW + (nt * 32 + l31) * 512
                                + (((ks * 2 + hi) ^ l7) << 4));
        acc[st * 2 + nt] = mfma32(af[ks], bfr, acc[st * 2 + nt]);
      }
    }
  }
}

__global__ __launch_bounds__(256, 2)
void tfs_kernel(
    const float* __restrict__ x,
    const float* __restrict__ mlp_b,
    const float* __restrict__ his_b,
    const float* __restrict__ cur_w,
    const float* __restrict__ cur_b,
    const float* __restrict__ wl_b,
    const float* __restrict__ gate_w,
    const float* __restrict__ gate_b,
    const float* __restrict__ ln_g,
    const float* __restrict__ ln_b,
    const unsigned short* __restrict__ wsp,
    float* __restrict__ out)
{
  __shared__ __align__(16) char smem[65536];

  const int tid = threadIdx.x;
  const int lane = tid & 63;
  const int l31 = lane & 31;
  const int hi = lane >> 5;
  const int l7 = lane & 7;
  const int w = tid >> 6;                 // 0..3
  const int wq = __builtin_amdgcn_readfirstlane(w);

  const int b = blockIdx.y;
  const int pidx = (blockIdx.x + b) & 15; // balance pidx across dispatch order
  const int p0 = pidx * 128;
  const int pw = p0 + w * 32;             // wave p-base (32 rows)
  const int pcol = pw + l31;              // softmax-owned p (lane column)
  const int qimax = (p0 + 127) >> 5;      // last qi with PV in this block

  const float* xb = x + (size_t)b * SEQ * DIM;
  const unsigned short* wlT  = wsp + WL_OFF;
  const unsigned short* hisT = wsp + HIS_OFF;
  const unsigned short* mlpT = wsp + MLP_OFF;
  const unsigned short* xTb  = wsp + XT_OFF + (size_t)b * DIM * SEQ;

  // ---- x fragments (wave's 32 p-rows) direct from global, f32->bf16 ----
  s8v xf[16];
  {
    const float* srcx = xb + (size_t)pcol * DIM;
    #pragma unroll
    for (int ks = 0; ks < 16; ++ks) {
      const int k0 = ks * 16 + hi * 8;
      f4v v0 = *(const f4v*)(srcx + k0);
      f4v v1 = *(const f4v*)(srcx + k0 + 4);
      u4v o;
      o[0] = pk2(v0[0], v0[1]); o[1] = pk2(v0[2], v0[3]);
      o[2] = pk2(v1[0], v1[1]); o[3] = pk2(v1[2], v1[3]);
      xf[ks] = *(s8v*)&o;
    }
  }

  // ---- Q = x @ his_w + his_b ----
  f16v accQ[8];
  #pragma unroll
  for (int i = 0; i < 8; ++i)
    #pragma unroll
    for (int e = 0; e < 16; ++e) accQ[i][e] = 0.f;
  gemm_stage32(hisT, xf, accQ, smem, wq, lane);
  __syncthreads();                        // last-stage reads drained
  // writeback Q -> QS [128 p][512B] swizzled (p&7)
  #pragma unroll
  for (int i = 0; i < 8; ++i) {
    const int n = i * 32 + l31;
    const float bias = his_b[n];
    #pragma unroll
    for (int r = 0; r < 16; ++r) {
      const int ploc = w * 32 + (r & 3) + 8 * (r >> 2) + 4 * hi;
      const int slot = (n >> 3) ^ (ploc & 7);
      *(unsigned short*)(smem + ploc * 512 + slot * 16 + (n & 7) * 2)
          = f2bf(accQ[i][r] + bias);
    }
  }
  __syncthreads();                        // Q visible
  s8v qf[16];                             // qi-invariant Q B-fragments
  #pragma unroll
  for (int ks = 0; ks < 16; ++ks)
    qf[ks] = *(const s8v*)(smem + (w * 32 + l31) * 512
                           + (((ks * 2 + hi) ^ l7) << 4));
  __syncthreads();                        // qf reads done; regions free

  // ---- stage K(0) @buf0, X(0) @buf0 ----
  {
    #pragma unroll
    for (int j = 0; j < 4; ++j) {
      const int q = wq * 8 + 2 * j + hi;
      dma16(wlT + ((size_t)q << 8) + ((l31 ^ (q & 7)) << 3),
            smem + wq * 4096 + j * 1024);
    }
    const int dr = lane >> 2, cx = lane & 3;
    #pragma unroll
    for (int j = 0; j < 4; ++j) {
      const int d = wq * 64 + j * 16 + dr;
      dma16(xTb + ((size_t)d << 11) + ((cx ^ ((d >> 1) & 3)) << 3),
            smem + BX0 + wq * 4096 + j * 1024);
    }
  }
  __syncthreads();                        // tiles 0 ready

  // ---- flash loop: 64 x 32-q tiles, 1 barrier/iter, wave-local softmax ----
  f16v accO[8];
  #pragma unroll
  for (int dt = 0; dt < 8; ++dt)
    #pragma unroll
    for (int e = 0; e < 16; ++e) accO[dt][e] = 0.f;
  float mrun = -1.0e30f, Zrun = 0.f;      // state for p = pcol

  #pragma unroll 1
  for (int qi = 0; qi < 64; ++qi) {
    const int q0 = qi * 32;
    char* bK = smem + ((qi & 1) << 14);
    char* nK = smem + ((~qi & 1) << 14);
    char* bX = smem + BX0 + ((qi & 1) << 14);
    char* nX = smem + BX0 + ((~qi & 1) << 14);

    // prefetch qi+1 (drained by loop-end barrier)
    if (qi < 63) {
      #pragma unroll
      for (int j = 0; j < 4; ++j) {
        const int q = wq * 8 + 2 * j + hi;
        dma16(wlT + ((size_t)(q0 + 32 + q) << 8) + ((l31 ^ (q & 7)) << 3),
              nK + wq * 4096 + j * 1024);
      }
      if (qi + 1 <= qimax) {
        const int dr = lane >> 2, cx = lane & 3;
        #pragma unroll
        for (int j = 0; j < 4; ++j) {
          const int d = wq * 64 + j * 16 + dr;
          dma16(xTb + ((size_t)d << 11) + (q0 + 32)
                    + ((cx ^ ((d >> 1) & 3)) << 3),
                nX + wq * 4096 + j * 1024);
        }
      }
    }

    // --- S^T = K @ Q (32x32x16): C[q row][p col], lane col = pcol ---
    f16v a0, a1;
    #pragma unroll
    for (int e = 0; e < 16; ++e) { a0[e] = 0.f; a1[e] = 0.f; }
    #pragma unroll
    for (int ks = 0; ks < 16; ks += 2) {
      s8v kf0 = *(const s8v*)(bK + l31 * 512 + (((ks * 2 + hi) ^ l7) << 4));
      s8v kf1 = *(const s8v*)(bK + l31 * 512 + ((((ks + 1) * 2 + hi) ^ l7) << 4));
      a0 = mfma32(kf0, qf[ks], a0);
      a1 = mfma32(kf1, qf[ks + 1], a1);
    }
    // S[r] for q = q0 + (r&3) + 8*(r>>2) + 4*hi ; + wl_b
    float S[16];
    #pragma unroll
    for (int j2 = 0; j2 < 4; ++j2) {
      const f4v wb = *(const f4v*)(wl_b + q0 + 8 * j2 + 4 * hi);
      #pragma unroll
      for (int c = 0; c < 4; ++c)
        S[j2 * 4 + c] = a0[j2 * 4 + c] + a1[j2 * 4 + c] + wb[c];
    }
    // row max: in-lane 16 + 1 shfl (partner holds complementary q's)
    float mt = S[0];
    #pragma unroll
    for (int r = 1; r < 16; ++r) mt = fmaxf(mt, S[r]);
    mt = fmaxf(mt, __shfl_xor(mt, 32, 64));
    const int grow = (mt > mrun) ? 1 : 0;
    const float mnew = fmaxf(mrun, mt);
    // P = exp(S - m), unmasked (denominator over all q)
    #pragma unroll
    for (int r = 0; r < 16; ++r)
      S[r] = __expf(fminf(S[r] - mnew, 0.f));
    float rs = 0.f;
    #pragma unroll
    for (int r = 0; r < 16; ++r) rs += S[r];
    rs += __shfl_xor(rs, 32, 64);

    // rescale (wave-uniform skip when no row max grew: alpha == 1 exactly)
    if (__any(grow)) {
      const float alpha = __expf(fminf(mrun - mnew, 0.f));
      float aR[16];
      #pragma unroll
      for (int r = 0; r < 16; ++r)
        aR[r] = __shfl(alpha, (r & 3) + 8 * (r >> 2) + 4 * hi, 64);
      #pragma unroll
      for (int dt = 0; dt < 8; ++dt)
        #pragma unroll
        for (int r = 0; r < 16; ++r) accO[dt][r] *= aR[r];
      Zrun = Zrun * alpha + rs;
    } else {
      Zrun += rs;
    }
    mrun = mnew;

    // --- PV (waves with any unmasked q) ---
    if (q0 <= pw + 31) {
      // mask (tril) + pack: A-frag for window w2 = regs 8*w2 + j (derived
      // from the swap23 xT permutation; see header comment)
      #pragma unroll
      for (int r = 0; r < 16; ++r) {
        const int qg = q0 + (r & 3) + 8 * (r >> 2) + 4 * hi;
        S[r] = (qg <= pcol) ? S[r] : 0.f;
      }
      s8v pa[2];
      #pragma unroll
      for (int w2 = 0; w2 < 2; ++w2) {
        u4v pk;
        pk[0] = pk2(S[8 * w2 + 0], S[8 * w2 + 1]);
        pk[1] = pk2(S[8 * w2 + 2], S[8 * w2 + 3]);
        pk[2] = pk2(S[8 * w2 + 4], S[8 * w2 + 5]);
        pk[3] = pk2(S[8 * w2 + 6], S[8 * w2 + 7]);
        pa[w2] = *(s8v*)&pk;
      }
      #pragma unroll
      for (int w2 = 0; w2 < 2; ++w2) {
        #pragma unroll
        for (int dt = 0; dt < 8; ++dt) {
          const int d = dt * 32 + l31;
          s8v bv = *(const s8v*)(bX + d * 64
                    + (((w2 * 2 + hi) ^ ((d >> 1) & 3)) << 4));
          accO[dt] = mfma32(pa[w2], bv, accO[dt]);
        }
      }
    }
    __syncthreads();  // buffers turn over; prefetch DMAs drained
  } // qi

  // ---- epilogue: agg = O/Z -> QS [128 p][512B] swizzled ----
  float izR[16];
  #pragma unroll
  for (int r = 0; r < 16; ++r) {
    const float z = __shfl(Zrun, (r & 3) + 8 * (r >> 2) + 4 * hi, 64);
    izR[r] = 1.0f / fmaxf(z, 1e-30f);
  }
  #pragma unroll
  for (int dt = 0; dt < 8; ++dt) {
    const int d = dt * 32 + l31;
    #pragma unroll
    for (int r = 0; r < 16; ++r) {
      const int ploc = w * 32 + (r & 3) + 8 * (r >> 2) + 4 * hi;
      const int slot = (d >> 3) ^ (ploc & 7);
      *(unsigned short*)(smem + ploc * 512 + slot * 16 + (d & 7) * 2)
          = f2bf(accO[dt][r] * izR[r]);
    }
  }
  __syncthreads();                        // agg visible
  s8v af[16];
  #pragma unroll
  for (int ks = 0; ks < 16; ++ks)
    af[ks] = *(const s8v*)(smem + (w * 32 + l31) * 512
                           + (((ks * 2 + hi) ^ l7) << 4));
  __syncthreads();                        // af read; WST region free

  // ---- H_hist = agg @ mlp_w ----
  f16v accH[8];
  #pragma unroll
  for (int i = 0; i < 8; ++i)
    #pragma unroll
    for (int e = 0; e < 16; ++e) accH[i][e] = 0.f;
  gemm_stage32(mlpT, af, accH, smem, wq, lane);

  // ---- cg[d] = cur_w[d,:]·gate_w ; cb  (@0, K-area dead) ----
  float* cgL = (float*)(smem);
  float* cbL = (float*)(smem + EP_CB);
  {
    const float* cw = cur_w + (size_t)tid * DIM;
    float s = 0.f;
    #pragma unroll 8
    for (int i = 0; i < 64; ++i) {
      f4v vc = *(const f4v*)(cw + i * 4);
      f4v vg = *(const f4v*)(gate_w + i * 4);
      s += vc[0] * vg[0] + vc[1] * vg[1] + vc[2] * vg[2] + vc[3] * vg[3];
    }
    cgL[tid] = s;
    if (tid == 0) {
      float s2 = 0.f;
      for (int j = 0; j < DIM; ++j) s2 += cur_b[j] * gate_w[j];
      cbL[0] = s2 + gate_b[0];
    }
  }
  __syncthreads();

  // ---- wcur[p] = x[p]·cg + cb ----
  float* wp = (float*)(smem + EP_WP);     // [128][2]
  {
    const int row = tid >> 1, sg = tid & 1;
    const float* xr = xb + (size_t)(p0 + row) * DIM + sg * 128;
    const float* cgp = cgL + sg * 128;
    float sacc = 0.f;
    #pragma unroll
    for (int i = 0; i < 32; ++i) {
      f4v xv4 = *(const f4v*)(xr + i * 4);
      sacc += xv4[0] * cgp[i * 4] + xv4[1] * cgp[i * 4 + 1]
            + xv4[2] * cgp[i * 4 + 2] + xv4[3] * cgp[i * 4 + 3];
    }
    wp[row * 2 + sg] = sacc;
  }
  __syncthreads();
  float* wcS = (float*)(smem + EP_WC);    // [128]
  if (tid < 128) {
    wcS[tid] = wp[tid * 2] + wp[tid * 2 + 1] + cbL[0];
  }
  __syncthreads();

  // ---- h = H_hist + mlp_b + wcur*x ; LN (reduce over 32 n-cols x 8 tiles) ----
  float mb8[8], g8[8], be8[8];
  #pragma unroll
  for (int i = 0; i < 8; ++i) {
    const int n = i * 32 + l31;
    mb8[i] = mlp_b[n];
    g8[i] = ln_g[n];
    be8[i] = ln_b[n];
  }
  float s1l[16], s2l[16];
  #pragma unroll
  for (int r = 0; r < 16; ++r) {
    const int ploc = w * 32 + (r & 3) + 8 * (r >> 2) + 4 * hi;
    const float wc_ = wcS[ploc];
    const float* xrow = xb + (size_t)(p0 + ploc) * DIM;
    float s1 = 0.f, s2 = 0.f;
    #pragma unroll
    for (int i = 0; i < 8; ++i) {
      const float xv = xrow[i * 32 + l31];
      const float v = accH[i][r] + mb8[i] + wc_ * xv;
      accH[i][r] = v;
      s1 += v;
      s2 += v * v;
    }
    s1l[r] = s1; s2l[r] = s2;
  }
  #pragma unroll
  for (int r = 0; r < 16; ++r) {
    float v1 = s1l[r], v2 = s2l[r];
    v1 += __shfl_xor(v1, 1, 64);  v2 += __shfl_xor(v2, 1, 64);
    v1 += __shfl_xor(v1, 2, 64);  v2 += __shfl_xor(v2, 2, 64);
    v1 += __shfl_xor(v1, 4, 64);  v2 += __shfl_xor(v2, 4, 64);
    v1 += __shfl_xor(v1, 8, 64);  v2 += __shfl_xor(v2, 8, 64);
    v1 += __shfl_xor(v1, 16, 64); v2 += __shfl_xor(v2, 16, 64);
    s1l[r] = v1; s2l[r] = v2;
  }
  #pragma unroll
  for (int r = 0; r < 16; ++r) {
    const int ploc = w * 32 + (r & 3) + 8 * (r >> 2) + 4 * hi;
    const float mean = s1l[r] * (1.0f / 256.0f);
    const float var = s2l[r] * (1.0f / 256.0f) - mean * mean;
    const float rstd = rsqrtf(fmaxf(var, 0.f) + 1e-5f);
    float* orow = out + ((size_t)b * SEQ + p0 + ploc) * DIM;
    #pragma unroll
    for (int i = 0; i < 8; ++i) {
      const float y = (accH[i][r] - mean) * rstd * g8[i] + be8[i];
      orow[i * 32 + l31] = y;
    }
  }

  // ---- origin passthrough ----
  {
    const int row = tid >> 1, cs = (tid & 1) * 128;
    const float* src = xb + (size_t)(p0 + row) * DIM + cs;
    float* dst = out + ORIGIN_OFF + ((size_t)b * SEQ + p0 + row) * DIM + cs;
    #pragma unroll
    for (int j = 0; j < 32; ++j)
      *(f4v*)(dst + j * 4) = *(const f4v*)(src + j * 4);
  }
}

extern "C" void kernel_launch(void* const* d_in, const int* in_sizes, int n_in,
                              void* d_out, int out_size, void* d_ws, size_t ws_size,
                              hipStream_t stream) {
  const float* x      = (const float*)d_in[0];
  const float* mlp_w  = (const float*)d_in[1];
  const float* mlp_b  = (const float*)d_in[2];
  const float* his_w  = (const float*)d_in[3];
  const float* his_b  = (const float*)d_in[4];
  const float* cur_w  = (const float*)d_in[5];
  const float* cur_b  = (const float*)d_in[6];
  const float* wl_w   = (const float*)d_in[7];
  const float* wl_b   = (const float*)d_in[8];
  const float* gate_w = (const float*)d_in[9];
  const float* gate_b = (const float*)d_in[10];
  const float* ln_g   = (const float*)d_in[11];
  const float* ln_b   = (const float*)d_in[12];

  unsigned short* ws = (unsigned short*)d_ws;

  prep_all<<<dim3(4256), 256, 0, stream>>>(x, wl_w, his_w, mlp_w, ws);
  tfs_kernel<<<dim3(16, 32), 256, 0, stream>>>(
      x, mlp_b, his_b, cur_w, cur_b, wl_b, gate_w, gate_b,
      ln_g, ln_b, ws, (float*)d_out);
}

// Round 9
// 627.258 us; speedup vs baseline: 1.1186x; 1.1186x over previous
//
#include <hip/hip_runtime.h>
#include <hip/hip_bf16.h>

typedef __attribute__((ext_vector_type(8))) short s8v;
typedef __attribute__((ext_vector_type(4))) float f4v;
typedef __attribute__((ext_vector_type(16))) float f16v;
typedef __attribute__((ext_vector_type(4))) unsigned int u4v;

#define BATCH 32
#define SEQ   2048
#define DIM   256
#define ORIGIN_OFF ((size_t)BATCH * SEQ * DIM)

// ---- workspace layout (units: bf16 shorts) ----
// xT  [32][256][2048] : x transposed per batch, bf16; q-positions PERMUTED
//                       within each 16-group: pos holds q = swap(bits2,3)(pos)
// wlT [2048 q][256 k] : wl_w^T bf16 (natural order)
// hisT/mlpT [256 n][256 k] bf16
#define XT_OFF  0ull
#define WL_OFF  16777216ull
#define HIS_OFF 17301504ull
#define MLP_OFF 17367040ull

// ---- LDS layout (bytes), total 65536 (2 blocks/CU, 4 waves each) ----
// flash : K dbuf @0      (2 x 16384)  [32 q][512B], chunk-XOR(q&7)
//         X dbuf @32768  (2 x 16384)  [256 d][64B], chunk-XOR((d>>1)&3)
// prolog/epilog alias:
//   QS (Q/agg) [64 p][512B] swizzled chunk-XOR(p&7) @0 (32768)
//   WST gemm W-stage [64 n][512B] @32768 (32768)
//   epilog small (all in dead K-area):
//     CG @0 (1024), CB @1024, WP @1040 (1024), WC @2064 (256),
//     S1X @2320 (512), S2X @2832 (512)
#define BX0   32768
#define WST   32768
#define EP_CB 1024
#define EP_WP 1040
#define EP_WC 2064
#define EP_S1 2320
#define EP_S2 2832

__device__ __forceinline__ unsigned short f2bf(float f) {
  __hip_bfloat16 h = __float2bfloat16(f);   // round-to-nearest-even
  return *reinterpret_cast<unsigned short*>(&h);
}
__device__ __forceinline__ f16v mfma32(s8v a, s8v b, f16v c) {
  return __builtin_amdgcn_mfma_f32_32x32x16_bf16(a, b, c, 0, 0, 0);
}
__device__ __forceinline__ unsigned int pk2(float lo, float hi) {
  return (unsigned int)f2bf(lo) | ((unsigned int)f2bf(hi) << 16);
}
// async global->LDS, 16B/lane; LDS dest = wave-uniform base + lane*16
__device__ __forceinline__ void dma16(const void* g, void* l) {
  __builtin_amdgcn_global_load_lds(
      (const __attribute__((address_space(1))) unsigned int*)g,
      (__attribute__((address_space(3))) unsigned int*)l, 16, 0, 0);
}

// ---------------- unified prep kernel (identical to r8, verified) ----------
__global__ __launch_bounds__(256) void prep_all(
    const float* __restrict__ x, const float* __restrict__ wl_w,
    const float* __restrict__ his_w, const float* __restrict__ mlp_w,
    unsigned short* __restrict__ ws)
{
  __shared__ unsigned short tile[64][72];   // 144B stride
  const int t = threadIdx.x;
  const int tb = blockIdx.x;
  const float* src; unsigned short* dst; int lds_, ldd_, r0, c0;
  bool isx = false;
  if (tb < 4096) {
    const int b = tb >> 7, rem = tb & 127;
    r0 = (rem >> 2) * 64;  c0 = (rem & 3) * 64;
    src = x + (size_t)b * SEQ * DIM;  lds_ = DIM;
    dst = ws + XT_OFF + (size_t)b * DIM * SEQ;  ldd_ = SEQ;
    isx = true;
  } else if (tb < 4224) {
    const int t2 = tb - 4096;
    r0 = (t2 >> 5) * 64;  c0 = (t2 & 31) * 64;
    src = wl_w;  lds_ = 2048;  dst = ws + WL_OFF;  ldd_ = 256;
  } else if (tb < 4240) {
    const int t2 = tb - 4224;
    r0 = (t2 >> 2) * 64;  c0 = (t2 & 3) * 64;
    src = his_w;  lds_ = 256;  dst = ws + HIS_OFF;  ldd_ = 256;
  } else {
    const int t2 = tb - 4240;
    r0 = (t2 >> 2) * 64;  c0 = (t2 & 3) * 64;
    src = mlp_w;  lds_ = 256;  dst = ws + MLP_OFF;  ldd_ = 256;
  }
  { // phase 1: coalesced row reads, 16B chunks at slot ch^(rr>>4)
    const int rr = t >> 2, cc = (t & 3) * 16;
    const float* s0 = src + (size_t)(r0 + rr) * lds_ + c0 + cc;
    f4v v0 = *(const f4v*)(s0);
    f4v v1 = *(const f4v*)(s0 + 4);
    f4v v2 = *(const f4v*)(s0 + 8);
    f4v v3 = *(const f4v*)(s0 + 12);
    u4v o0, o1;
    o0[0] = pk2(v0[0], v0[1]); o0[1] = pk2(v0[2], v0[3]);
    o0[2] = pk2(v1[0], v1[1]); o0[3] = pk2(v1[2], v1[3]);
    o1[0] = pk2(v2[0], v2[1]); o1[1] = pk2(v2[2], v2[3]);
    o1[2] = pk2(v3[0], v3[1]); o1[3] = pk2(v3[2], v3[3]);
    const int swz = rr >> 4;
    const int ch = cc >> 3;          // 0,2,4,6
    unsigned short* trow = &tile[rr][0];
    *(u4v*)(trow + ((ch ^ swz) << 3)) = o0;
    *(u4v*)(trow + (((ch + 1) ^ swz) << 3)) = o1;
  }
  __syncthreads();
  {
    const int cl = t >> 2, sg = t & 3;
    const int el = cl & 7;
    const int chb = ((cl >> 3) ^ sg) << 3;   // rA>>4 == sg in all cases below
    u4v o0, o1;
    if (isx) { // permuted: output pos e holds source q = sg*16 + swap23(e)
      const int pe0[4] = {0, 2, 8, 10};   // swap23 of e = 0,2,4,6
      const int pe1[4] = {4, 6, 12, 14};  // swap23 of e = 8,10,12,14
      #pragma unroll
      for (int j = 0; j < 4; ++j) {
        const int rA = sg * 16 + pe0[j];
        o0[j] = (unsigned int)tile[rA][chb + el]
              | ((unsigned int)tile[rA + 1][chb + el] << 16);
      }
      #pragma unroll
      for (int j = 0; j < 4; ++j) {
        const int rA = sg * 16 + pe1[j];
        o1[j] = (unsigned int)tile[rA][chb + el]
              | ((unsigned int)tile[rA + 1][chb + el] << 16);
      }
    } else {   // identity order
      #pragma unroll
      for (int j = 0; j < 4; ++j) {
        const int rA = sg * 16 + 2 * j;
        o0[j] = (unsigned int)tile[rA][chb + el]
              | ((unsigned int)tile[rA + 1][chb + el] << 16);
      }
      #pragma unroll
      for (int j = 0; j < 4; ++j) {
        const int rA = sg * 16 + 8 + 2 * j;
        o1[j] = (unsigned int)tile[rA][chb + el]
              | ((unsigned int)tile[rA + 1][chb + el] << 16);
      }
    }
    unsigned short* d0 = dst + (size_t)(c0 + cl) * ldd_ + r0 + sg * 16;
    *(u4v*)d0 = o0;
    *(u4v*)(d0 + 8) = o1;
  }
}

// ---------------- main kernel ----------------

// Pair-split GEMM: wave (g,h2) accumulates only its n-half (stages 2h2,2h2+1).
// acc[si*2+nt]: n = (2*h2+si)*64 + nt*32 + (lane&31). All waves stage DMA.
__device__ __forceinline__ void gemm_stage32(
    const unsigned short* __restrict__ Wt, const s8v (&af)[16],
    f16v (&acc)[4], char* smem_, int wq, int lane, int h2)
{
  char* sW = smem_ + WST;
  const int hi = lane >> 5, l31 = lane & 31, l7 = lane & 7;
  for (int st = 0; st < 4; ++st) {
    if (st) __syncthreads();             // prior-stage reads drained
    #pragma unroll
    for (int j = 0; j < 8; ++j) {
      const int row = wq * 16 + 2 * j + hi;
      dma16(Wt + (size_t)(st * 64 + row) * 256 + ((l31 ^ (row & 7)) << 3),
            sW + wq * 8192 + j * 1024);
    }
    __syncthreads();                     // DMA complete (implicit vmcnt(0))
    if ((st >> 1) == h2) {               // wave-uniform gate
      const int si = st & 1;
      #pragma unroll
      for (int ks = 0; ks < 16; ++ks) {
        #pragma unroll
        for (int nt = 0; nt < 2; ++nt) {
          s8v bfr = *(const s8v*)(sW + (nt * 32 + l31) * 512
                                  + (((ks * 2 + hi) ^ l7) << 4));
          acc[si * 2 + nt] = mfma32(af[ks], bfr, acc[si * 2 + nt]);
        }
      }
    }
  }
}

__global__ __launch_bounds__(256, 2)
void tfs_kernel(
    const float* __restrict__ x,
    const float* __restrict__ mlp_b,
    const float* __restrict__ his_b,
    const float* __restrict__ cur_w,
    const float* __restrict__ cur_b,
    const float* __restrict__ wl_b,
    const float* __restrict__ gate_w,
    const float* __restrict__ gate_b,
    const float* __restrict__ ln_g,
    const float* __restrict__ ln_b,
    const unsigned short* __restrict__ wsp,
    float* __restrict__ out)
{
  __shared__ __align__(16) char smem[65536];

  const int tid = threadIdx.x;
  const int lane = tid & 63;
  const int l31 = lane & 31;
  const int hi = lane >> 5;
  const int l7 = lane & 7;
  const int w = tid >> 6;                 // 0..3
  const int g = w >> 1;                   // p-subgroup (0,1)
  const int h2 = w & 1;                   // d/n-half (0,1)
  const int wq = __builtin_amdgcn_readfirstlane(w);

  const int b = blockIdx.y;
  const int pidx = (blockIdx.x + b) & 31; // balance pidx across dispatch order
  const int p0 = pidx * 64;
  const int pw = p0 + g * 32;             // wave p-base (32 rows)
  const int pcol = pw + l31;              // softmax-owned p (lane column)
  const int qimax = 2 * pidx + 1;         // last qi with PV in this block

  const float* xb = x + (size_t)b * SEQ * DIM;
  const unsigned short* wlT  = wsp + WL_OFF;
  const unsigned short* hisT = wsp + HIS_OFF;
  const unsigned short* mlpT = wsp + MLP_OFF;
  const unsigned short* xTb  = wsp + XT_OFF + (size_t)b * DIM * SEQ;

  // ---- x fragments (wave's 32 p-rows) direct from global, f32->bf16 ----
  s8v xf[16];
  {
    const float* srcx = xb + (size_t)pcol * DIM;
    #pragma unroll
    for (int ks = 0; ks < 16; ++ks) {
      const int k0 = ks * 16 + hi * 8;
      f4v v0 = *(const f4v*)(srcx + k0);
      f4v v1 = *(const f4v*)(srcx + k0 + 4);
      u4v o;
      o[0] = pk2(v0[0], v0[1]); o[1] = pk2(v0[2], v0[3]);
      o[2] = pk2(v1[0], v1[1]); o[3] = pk2(v1[2], v1[3]);
      xf[ks] = *(s8v*)&o;
    }
  }

  // ---- Q = x @ his_w + his_b (n-half per wave) ----
  f16v accQ[4];
  #pragma unroll
  for (int i = 0; i < 4; ++i)
    #pragma unroll
    for (int e = 0; e < 16; ++e) accQ[i][e] = 0.f;
  gemm_stage32(hisT, xf, accQ, smem, wq, lane, h2);
  __syncthreads();                        // last-stage reads drained
  // writeback Q -> QS [64 p][512B] swizzled (p&7); pair halves disjoint in n
  #pragma unroll
  for (int i = 0; i < 4; ++i) {
    const int n = h2 * 128 + (i >> 1) * 64 + (i & 1) * 32 + l31;
    const float bias = his_b[n];
    #pragma unroll
    for (int r = 0; r < 16; ++r) {
      const int ploc = g * 32 + (r & 3) + 8 * (r >> 2) + 4 * hi;
      const int slot = (n >> 3) ^ (ploc & 7);
      *(unsigned short*)(smem + ploc * 512 + slot * 16 + (n & 7) * 2)
          = f2bf(accQ[i][r] + bias);
    }
  }
  __syncthreads();                        // Q visible (cross-wave halves)
  s8v qf[16];                             // qi-invariant Q B-fragments (full K)
  #pragma unroll
  for (int ks = 0; ks < 16; ++ks)
    qf[ks] = *(const s8v*)(smem + (g * 32 + l31) * 512
                           + (((ks * 2 + hi) ^ l7) << 4));
  __syncthreads();                        // qf reads done; regions free

  // ---- stage K(0) @buf0, X(0) @buf0 ----
  {
    #pragma unroll
    for (int j = 0; j < 4; ++j) {
      const int q = wq * 8 + 2 * j + hi;
      dma16(wlT + ((size_t)q << 8) + ((l31 ^ (q & 7)) << 3),
            smem + wq * 4096 + j * 1024);
    }
    const int dr = lane >> 2, cx = lane & 3;
    #pragma unroll
    for (int j = 0; j < 4; ++j) {
      const int d = wq * 64 + j * 16 + dr;
      dma16(xTb + ((size_t)d << 11) + ((cx ^ ((d >> 1) & 3)) << 3),
            smem + BX0 + wq * 4096 + j * 1024);
    }
  }
  __syncthreads();                        // tiles 0 ready

  // ---- flash loop: 64 x 32-q tiles, 1 barrier/iter, wave-local softmax ----
  f16v accO[4];
  #pragma unroll
  for (int dt = 0; dt < 4; ++dt)
    #pragma unroll
    for (int e = 0; e < 16; ++e) accO[dt][e] = 0.f;
  float mrun = -1.0e30f, Zrun = 0.f;      // state for p = pcol

  #pragma unroll 1
  for (int qi = 0; qi < 64; ++qi) {
    const int q0 = qi * 32;
    char* bK = smem + ((qi & 1) << 14);
    char* nK = smem + ((~qi & 1) << 14);
    char* bX = smem + BX0 + ((qi & 1) << 14);
    char* nX = smem + BX0 + ((~qi & 1) << 14);

    // prefetch qi+1 (drained by loop-end barrier)
    if (qi < 63) {
      #pragma unroll
      for (int j = 0; j < 4; ++j) {
        const int q = wq * 8 + 2 * j + hi;
        dma16(wlT + ((size_t)(q0 + 32 + q) << 8) + ((l31 ^ (q & 7)) << 3),
              nK + wq * 4096 + j * 1024);
      }
      if (qi + 1 <= qimax) {
        const int dr = lane >> 2, cx = lane & 3;
        #pragma unroll
        for (int j = 0; j < 4; ++j) {
          const int d = wq * 64 + j * 16 + dr;
          dma16(xTb + ((size_t)d << 11) + (q0 + 32)
                    + ((cx ^ ((d >> 1) & 3)) << 3),
                nX + wq * 4096 + j * 1024);
        }
      }
    }

    // --- S^T = K @ Q (32x32x16): C[q row][p col], lane col = pcol ---
    f16v a0, a1;
    #pragma unroll
    for (int e = 0; e < 16; ++e) { a0[e] = 0.f; a1[e] = 0.f; }
    #pragma unroll
    for (int ks = 0; ks < 16; ks += 2) {
      s8v kf0 = *(const s8v*)(bK + l31 * 512 + (((ks * 2 + hi) ^ l7) << 4));
      s8v kf1 = *(const s8v*)(bK + l31 * 512 + ((((ks + 1) * 2 + hi) ^ l7) << 4));
      a0 = mfma32(kf0, qf[ks], a0);
      a1 = mfma32(kf1, qf[ks + 1], a1);
    }
    // S[r] for q = q0 + (r&3) + 8*(r>>2) + 4*hi ; + wl_b
    float S[16];
    #pragma unroll
    for (int j2 = 0; j2 < 4; ++j2) {
      const f4v wb = *(const f4v*)(wl_b + q0 + 8 * j2 + 4 * hi);
      #pragma unroll
      for (int c = 0; c < 4; ++c)
        S[j2 * 4 + c] = a0[j2 * 4 + c] + a1[j2 * 4 + c] + wb[c];
    }
    // row max: in-lane 16 + 1 shfl (partner lane holds complementary q's)
    float mt = S[0];
    #pragma unroll
    for (int r = 1; r < 16; ++r) mt = fmaxf(mt, S[r]);
    mt = fmaxf(mt, __shfl_xor(mt, 32, 64));
    const int grow = (mt > mrun) ? 1 : 0;
    const float mnew = fmaxf(mrun, mt);
    // P = exp(S - m), unmasked (denominator over all q)
    #pragma unroll
    for (int r = 0; r < 16; ++r)
      S[r] = __expf(fminf(S[r] - mnew, 0.f));
    float rs = 0.f;
    #pragma unroll
    for (int r = 0; r < 16; ++r) rs += S[r];
    rs += __shfl_xor(rs, 32, 64);

    // rescale (wave-uniform skip when no row max grew: alpha == 1 exactly)
    if (__any(grow)) {
      const float alpha = __expf(fminf(mrun - mnew, 0.f));
      float aR[16];
      #pragma unroll
      for (int r = 0; r < 16; ++r)
        aR[r] = __shfl(alpha, (r & 3) + 8 * (r >> 2) + 4 * hi, 64);
      #pragma unroll
      for (int dt = 0; dt < 4; ++dt)
        #pragma unroll
        for (int r = 0; r < 16; ++r) accO[dt][r] *= aR[r];
      Zrun = Zrun * alpha + rs;
    } else {
      Zrun += rs;
    }
    mrun = mnew;

    // --- PV (this wave's d-half) ---
    if (q0 <= pw + 31) {
      #pragma unroll
      for (int r = 0; r < 16; ++r) {
        const int qg = q0 + (r & 3) + 8 * (r >> 2) + 4 * hi;
        S[r] = (qg <= pcol) ? S[r] : 0.f;
      }
      s8v pa[2];
      #pragma unroll
      for (int w2 = 0; w2 < 2; ++w2) {
        u4v pk;
        pk[0] = pk2(S[8 * w2 + 0], S[8 * w2 + 1]);
        pk[1] = pk2(S[8 * w2 + 2], S[8 * w2 + 3]);
        pk[2] = pk2(S[8 * w2 + 4], S[8 * w2 + 5]);
        pk[3] = pk2(S[8 * w2 + 6], S[8 * w2 + 7]);
        pa[w2] = *(s8v*)&pk;
      }
      #pragma unroll
      for (int w2 = 0; w2 < 2; ++w2) {
        #pragma unroll
        for (int dt = 0; dt < 4; ++dt) {
          const int d = h2 * 128 + dt * 32 + l31;
          s8v bv = *(const s8v*)(bX + d * 64
                    + (((w2 * 2 + hi) ^ ((d >> 1) & 3)) << 4));
          accO[dt] = mfma32(pa[w2], bv, accO[dt]);
        }
      }
    }
    __syncthreads();  // buffers turn over; prefetch DMAs drained
  } // qi

  // ---- epilogue: agg = O/Z -> QS [64 p][512B] swizzled (d-half) ----
  float izR[16];
  #pragma unroll
  for (int r = 0; r < 16; ++r) {
    const float z = __shfl(Zrun, (r & 3) + 8 * (r >> 2) + 4 * hi, 64);
    izR[r] = 1.0f / fmaxf(z, 1e-30f);
  }
  #pragma unroll
  for (int dt = 0; dt < 4; ++dt) {
    const int d = h2 * 128 + dt * 32 + l31;
    #pragma unroll
    for (int r = 0; r < 16; ++r) {
      const int ploc = g * 32 + (r & 3) + 8 * (r >> 2) + 4 * hi;
      const int slot = (d >> 3) ^ (ploc & 7);
      *(unsigned short*)(smem + ploc * 512 + slot * 16 + (d & 7) * 2)
          = f2bf(accO[dt][r] * izR[r]);
    }
  }
  __syncthreads();                        // agg visible
  s8v af[16];
  #pragma unroll
  for (int ks = 0; ks < 16; ++ks)
    af[ks] = *(const s8v*)(smem + (g * 32 + l31) * 512
                           + (((ks * 2 + hi) ^ l7) << 4));
  __syncthreads();                        // af read; WST region free

  // ---- H_hist = agg @ mlp_w (n-half per wave) ----
  f16v accH[4];
  #pragma unroll
  for (int i = 0; i < 4; ++i)
    #pragma unroll
    for (int e = 0; e < 16; ++e) accH[i][e] = 0.f;
  gemm_stage32(mlpT, af, accH, smem, wq, lane, h2);

  // ---- cg[d] = cur_w[d,:]·gate_w ; cb  (@0, agg consumed) ----
  float* cgL = (float*)(smem);
  float* cbL = (float*)(smem + EP_CB);
  {
    const float* cw = cur_w + (size_t)tid * DIM;
    float s = 0.f;
    #pragma unroll 8
    for (int i = 0; i < 64; ++i) {
      f4v vc = *(const f4v*)(cw + i * 4);
      f4v vg = *(const f4v*)(gate_w + i * 4);
      s += vc[0] * vg[0] + vc[1] * vg[1] + vc[2] * vg[2] + vc[3] * vg[3];
    }
    cgL[tid] = s;
    if (tid == 0) {
      float s2 = 0.f;
      for (int j = 0; j < DIM; ++j) s2 += cur_b[j] * gate_w[j];
      cbL[0] = s2 + gate_b[0];
    }
  }
  __syncthreads();

  // ---- wcur[p] = x[p]·cg + cb ----
  float* wp = (float*)(smem + EP_WP);     // [64][4]
  {
    const int row = tid >> 2, sg = tid & 3;
    const float* xr = xb + (size_t)(p0 + row) * DIM + sg * 64;
    const float* cgp = cgL + sg * 64;
    float sacc = 0.f;
    #pragma unroll
    for (int i = 0; i < 16; ++i) {
      f4v xv4 = *(const f4v*)(xr + i * 4);
      sacc += xv4[0] * cgp[i * 4] + xv4[1] * cgp[i * 4 + 1]
            + xv4[2] * cgp[i * 4 + 2] + xv4[3] * cgp[i * 4 + 3];
    }
    wp[row * 4 + sg] = sacc;
  }
  __syncthreads();
  float* wcS = (float*)(smem + EP_WC);    // [64]
  if (tid < 64) {
    wcS[tid] = wp[tid * 4] + wp[tid * 4 + 1] + wp[tid * 4 + 2] + wp[tid * 4 + 3]
             + cbL[0];
  }
  __syncthreads();

  // ---- h = H_hist + mlp_b + wcur*x ; LN (pair-exchange row sums) ----
  float mb4[4], g4[4], be4[4];
  #pragma unroll
  for (int i = 0; i < 4; ++i) {
    const int n = h2 * 128 + (i >> 1) * 64 + (i & 1) * 32 + l31;
    mb4[i] = mlp_b[n];
    g4[i] = ln_g[n];
    be4[i] = ln_b[n];
  }
  float s1l[16], s2l[16];
  #pragma unroll
  for (int r = 0; r < 16; ++r) {
    const int ploc = g * 32 + (r & 3) + 8 * (r >> 2) + 4 * hi;
    const float wc_ = wcS[ploc];
    const float* xrow = xb + (size_t)(p0 + ploc) * DIM;
    float s1 = 0.f, s2 = 0.f;
    #pragma unroll
    for (int i = 0; i < 4; ++i) {
      const int n = h2 * 128 + (i >> 1) * 64 + (i & 1) * 32 + l31;
      const float xv = xrow[n];
      const float v = accH[i][r] + mb4[i] + wc_ * xv;
      accH[i][r] = v;
      s1 += v;
      s2 += v * v;
    }
    s1l[r] = s1; s2l[r] = s2;
  }
  #pragma unroll
  for (int r = 0; r < 16; ++r) {   // reduce within 32-lane half
    float v1 = s1l[r], v2 = s2l[r];
    v1 += __shfl_xor(v1, 1, 64);  v2 += __shfl_xor(v2, 1, 64);
    v1 += __shfl_xor(v1, 2, 64);  v2 += __shfl_xor(v2, 2, 64);
    v1 += __shfl_xor(v1, 4, 64);  v2 += __shfl_xor(v2, 4, 64);
    v1 += __shfl_xor(v1, 8, 64);  v2 += __shfl_xor(v2, 8, 64);
    v1 += __shfl_xor(v1, 16, 64); v2 += __shfl_xor(v2, 16, 64);
    s1l[r] = v1; s2l[r] = v2;
  }
  // exchange partial sums across the pair (n-halves)
  float* S1X = (float*)(smem + EP_S1);    // [2 h2][64 p]
  float* S2X = (float*)(smem + EP_S2);
  if (l31 == 0) {                         // lanes 0 (hi=0) and 32 (hi=1)
    #pragma unroll
    for (int r = 0; r < 16; ++r) {
      const int idx = g * 32 + (r & 3) + 8 * (r >> 2) + 4 * hi;
      S1X[h2 * 64 + idx] = s1l[r];
      S2X[h2 * 64 + idx] = s2l[r];
    }
  }
  __syncthreads();
  #pragma unroll
  for (int r = 0; r < 16; ++r) {
    const int ploc = g * 32 + (r & 3) + 8 * (r >> 2) + 4 * hi;
    const float S1 = S1X[ploc] + S1X[64 + ploc];
    const float S2 = S2X[ploc] + S2X[64 + ploc];
    const float mean = S1 * (1.0f / 256.0f);
    const float var = S2 * (1.0f / 256.0f) - mean * mean;
    const float rstd = rsqrtf(fmaxf(var, 0.f) + 1e-5f);
    float* orow = out + ((size_t)b * SEQ + p0 + ploc) * DIM;
    #pragma unroll
    for (int i = 0; i < 4; ++i) {
      const int n = h2 * 128 + (i >> 1) * 64 + (i & 1) * 32 + l31;
      const float y = (accH[i][r] - mean) * rstd * g4[i] + be4[i];
      orow[n] = y;
    }
  }

  // ---- origin passthrough ----
  {
    const int row = tid >> 2, cs = (tid & 3) * 64;
    const float* src = xb + (size_t)(p0 + row) * DIM + cs;
    float* dst = out + ORIGIN_OFF + ((size_t)b * SEQ + p0 + row) * DIM + cs;
    #pragma unroll
    for (int j = 0; j < 16; ++j)
      *(f4v*)(dst + j * 4) = *(const f4v*)(src + j * 4);
  }
}

extern "C" void kernel_launch(void* const* d_in, const int* in_sizes, int n_in,
                              void* d_out, int out_size, void* d_ws, size_t ws_size,
                              hipStream_t stream) {
  const float* x      = (const float*)d_in[0];
  const float* mlp_w  = (const float*)d_in[1];
  const float* mlp_b  = (const float*)d_in[2];
  const float* his_w  = (const float*)d_in[3];
  const float* his_b  = (const float*)d_in[4];
  const float* cur_w  = (const float*)d_in[5];
  const float* cur_b  = (const float*)d_in[6];
  const float* wl_w   = (const float*)d_in[7];
  const float* wl_b   = (const float*)d_in[8];
  const float* gate_w = (const float*)d_in[9];
  const float* gate_b = (const float*)d_in[10];
  const float* ln_g   = (const float*)d_in[11];
  const float* ln_b   = (const float*)d_in[12];

  unsigned short* ws = (unsigned short*)d_ws;

  prep_all<<<dim3(4256), 256, 0, stream>>>(x, wl_w, his_w, mlp_w, ws);
  tfs_kernel<<<dim3(32, 32), 256, 0, stream>>>(
      x, mlp_b, his_b, cur_w, cur_b, wl_b, gate_w, gate_b,
      ln_g, ln_b, ws, (float*)d_out);
}